// Round 1
// baseline (674.688 us; speedup 1.0000x reference)
//
#include <hip/hip_runtime.h>
#include <cstdint>
#include <cmath>

#define B_ 16
#define F_ 256
#define T_ 4096
#define L_ 128
#define TC_ 2048
#define D_ 128
#define M_ 1024
#define NROWS_ 32768  // B_*TC_

#define PAD 132  // 128 + 4; multiple of 4 keeps float4 LDS reads 16B-aligned

// ---------------- GEMM1: x[b][t][l] = sum_f in[b][f][t] * w1[l][f] ----------
__global__ __launch_bounds__(256) void gemm1_kernel(
    const float* __restrict__ in, const float* __restrict__ w1,
    float* __restrict__ x) {
  __shared__ float As[32 * PAD];  // [ff][tt]   (direct: in is [f][t], t contiguous)
  __shared__ float Bs[32 * PAD];  // [ff][ll]   (w1 transposed)
  const int tid = threadIdx.x;
  const int blk = blockIdx.x;
  const int b = blk >> 5;
  const int t0 = (blk & 31) << 7;
  const int tm = tid & 15;  // l-group
  const int tr = tid >> 4;  // t-group
  const float* inb = in + (size_t)b * F_ * T_;
  float acc[8][8];
#pragma unroll
  for (int i = 0; i < 8; ++i)
#pragma unroll
    for (int j = 0; j < 8; ++j) acc[i][j] = 0.f;

  for (int f0 = 0; f0 < F_; f0 += 32) {
#pragma unroll
    for (int it = 0; it < 4; ++it) {
      int e = tid + it * 256;
      int ff = e >> 5, q = e & 31;
      float4 v = *(const float4*)(inb + (size_t)(f0 + ff) * T_ + t0 + q * 4);
      *(float4*)(&As[ff * PAD + q * 4]) = v;
    }
#pragma unroll
    for (int it = 0; it < 4; ++it) {
      int e = tid + it * 256;
      int l = e >> 3, q = e & 7;
      float4 v = *(const float4*)(w1 + l * F_ + f0 + q * 4);
      Bs[(q * 4 + 0) * PAD + l] = v.x;
      Bs[(q * 4 + 1) * PAD + l] = v.y;
      Bs[(q * 4 + 2) * PAD + l] = v.z;
      Bs[(q * 4 + 3) * PAD + l] = v.w;
    }
    __syncthreads();
#pragma unroll
    for (int ff = 0; ff < 32; ++ff) {
      float a[8], w[8];
      *(float4*)&a[0] = *(const float4*)&As[ff * PAD + tr * 8];
      *(float4*)&a[4] = *(const float4*)&As[ff * PAD + tr * 8 + 4];
      *(float4*)&w[0] = *(const float4*)&Bs[ff * PAD + tm * 8];
      *(float4*)&w[4] = *(const float4*)&Bs[ff * PAD + tm * 8 + 4];
#pragma unroll
      for (int i = 0; i < 8; ++i)
#pragma unroll
        for (int j = 0; j < 8; ++j) acc[i][j] = fmaf(a[i], w[j], acc[i][j]);
    }
    __syncthreads();
  }
  float* xb = x + ((size_t)b * T_ + t0) * L_;
#pragma unroll
  for (int i = 0; i < 8; ++i) {
    float* dst = xb + (size_t)(tr * 8 + i) * L_ + tm * 8;
    *(float4*)(dst) = make_float4(acc[i][0], acc[i][1], acc[i][2], acc[i][3]);
    *(float4*)(dst + 4) = make_float4(acc[i][4], acc[i][5], acc[i][6], acc[i][7]);
  }
}

// ---------------- c2[k*M+m] = ||emb_m||^2 ----------------------------------
__global__ __launch_bounds__(256) void c2_kernel(const float* __restrict__ cbs,
                                                 float* __restrict__ c2) {
  int m = blockIdx.x * 256 + threadIdx.x;  // 0..2047 (covers both codebooks)
  const float* row = cbs + (size_t)m * D_;
  float s = 0.f;
#pragma unroll
  for (int d = 0; d < D_; d += 4) {
    float4 v = *(const float4*)(row + d);
    s += v.x * v.x;
    s += v.y * v.y;
    s += v.z * v.z;
    s += v.w * v.w;
  }
  c2[m] = s;
}

// ---------------- VQ: dist + gumbel argmax + gather + index write ----------
// score(n,m) = -5*(||e_m||^2 - 2*x_n.e_m) + g[n,m]   (row-constant terms and
// monotone transforms dropped -- argmax-invariant)
__global__ __launch_bounds__(256) void vq_kernel(
    const float* __restrict__ x, const float* __restrict__ cbs,
    const float* __restrict__ gum, const float* __restrict__ c2,
    float* __restrict__ vq_feat, float* __restrict__ qinds) {
  __shared__ float smem[2 * 32 * PAD];
  __shared__ int widx[128];
  float* Xs = smem;             // xT[dd][r]
  float* Es = smem + 32 * PAD;  // embT[dd][mm]
  const int tid = threadIdx.x;
  const int blk = blockIdx.x;
  const int cb = blk >> 8;          // codebook
  const int n0 = (blk & 255) << 7;  // first row of this block
  const int tm = tid & 15;          // m-group
  const int tr = tid >> 4;          // row-group
  const float* cbp = cbs + (size_t)cb * M_ * D_;
  const float* gp = gum + (size_t)cb * NROWS_ * M_;
  const float* c2p = c2 + cb * M_;

  float best[8];
  int bidx[8];
#pragma unroll
  for (int i = 0; i < 8; ++i) {
    best[i] = -INFINITY;
    bidx[i] = 0;
  }

  for (int mt = 0; mt < 8; ++mt) {
    const int m0 = mt << 7;
    float acc[8][8];
#pragma unroll
    for (int i = 0; i < 8; ++i)
#pragma unroll
      for (int j = 0; j < 8; ++j) acc[i][j] = 0.f;

    for (int d0 = 0; d0 < D_; d0 += 32) {
      const int cf = d0 >> 6;   // which combined frame
      const int j0 = d0 & 63;   // offset within the 64-wide l-slice
      // stage xT[dd][r]: row n=(b,tc), d = cf*64+j -> x[b][2tc+cf][cb*64+j]
#pragma unroll
      for (int it = 0; it < 4; ++it) {
        int e = tid + it * 256;
        int r = e >> 3, q = e & 7;
        int n = n0 + r;
        int bb = n >> 11, tc = n & 2047;
        const float* src =
            x + ((size_t)bb * T_ + 2 * tc + cf) * L_ + cb * 64 + j0 + q * 4;
        float4 v = *(const float4*)src;
        Xs[(q * 4 + 0) * PAD + r] = v.x;
        Xs[(q * 4 + 1) * PAD + r] = v.y;
        Xs[(q * 4 + 2) * PAD + r] = v.z;
        Xs[(q * 4 + 3) * PAD + r] = v.w;
      }
      // stage embT[dd][mm]
#pragma unroll
      for (int it = 0; it < 4; ++it) {
        int e = tid + it * 256;
        int mm = e >> 3, q = e & 7;
        const float* src = cbp + (size_t)(m0 + mm) * D_ + d0 + q * 4;
        float4 v = *(const float4*)src;
        Es[(q * 4 + 0) * PAD + mm] = v.x;
        Es[(q * 4 + 1) * PAD + mm] = v.y;
        Es[(q * 4 + 2) * PAD + mm] = v.z;
        Es[(q * 4 + 3) * PAD + mm] = v.w;
      }
      __syncthreads();
#pragma unroll
      for (int dd = 0; dd < 32; ++dd) {
        float a[8], w[8];
        *(float4*)&a[0] = *(const float4*)&Xs[dd * PAD + tr * 8];
        *(float4*)&a[4] = *(const float4*)&Xs[dd * PAD + tr * 8 + 4];
        *(float4*)&w[0] = *(const float4*)&Es[dd * PAD + tm * 8];
        *(float4*)&w[4] = *(const float4*)&Es[dd * PAD + tm * 8 + 4];
#pragma unroll
        for (int i = 0; i < 8; ++i)
#pragma unroll
          for (int j = 0; j < 8; ++j) acc[i][j] = fmaf(a[i], w[j], acc[i][j]);
      }
      __syncthreads();
    }
    // scores for this m-tile
    float cc[8];
    *(float4*)&cc[0] = *(const float4*)(c2p + m0 + tm * 8);
    *(float4*)&cc[4] = *(const float4*)(c2p + m0 + tm * 8 + 4);
#pragma unroll
    for (int i = 0; i < 8; ++i) {
      int n = n0 + tr * 8 + i;
      const float* grow = gp + (size_t)n * M_ + m0 + tm * 8;
      float g[8];
      *(float4*)&g[0] = *(const float4*)grow;
      *(float4*)&g[4] = *(const float4*)(grow + 4);
#pragma unroll
      for (int j = 0; j < 8; ++j) {
        float dist = cc[j] - 2.f * acc[i][j];
        float sc = fmaf(-5.f, dist, g[j]);
        if (sc > best[i]) {  // strict > keeps first max (ascending m in-thread)
          best[i] = sc;
          bidx[i] = m0 + tm * 8 + j;
        }
      }
    }
  }
  // block-level argmax reduce (overlay staging LDS; stride 17 avoids conflicts)
  float* rbest = smem;                  // [128][17]
  int* ridx = (int*)(smem + 128 * 17);  // [128][17]
#pragma unroll
  for (int i = 0; i < 8; ++i) {
    rbest[(tr * 8 + i) * 17 + tm] = best[i];
    ridx[(tr * 8 + i) * 17 + tm] = bidx[i];
  }
  __syncthreads();
  if (tid < 128) {
    float bv = rbest[tid * 17];
    int bi = ridx[tid * 17];
#pragma unroll
    for (int k = 1; k < 16; ++k) {
      float v = rbest[tid * 17 + k];
      int ii = ridx[tid * 17 + k];
      if (v > bv || (v == bv && ii < bi)) {  // ties -> smallest index (jnp.argmax)
        bv = v;
        bi = ii;
      }
    }
    widx[tid] = bi;
    int n = n0 + tid;
    qinds[(size_t)n * 2 + cb] = (float)bi;  // quant_inds as float values
  }
  __syncthreads();
  // gather: vq_feat[b][2tc+cf][cb*64+j] = emb[widx][cf*64+j]
  const int jj = (tid & 15) * 4;
  for (int seg = tid >> 4; seg < 256; seg += 16) {
    int r = seg >> 1, cf = seg & 1;
    int wi = widx[r];
    float4 v = *(const float4*)(cbp + (size_t)wi * D_ + cf * 64 + jj);
    int n = n0 + r;
    int bb = n >> 11, tc = n & 2047;
    float* dst = vq_feat + ((size_t)bb * T_ + 2 * tc + cf) * L_ + cb * 64 + jj;
    *(float4*)dst = v;
  }
}

// ---------------- GEMM2: out[b][f][t] = sum_l vq[b][t][l] * w2[f][l] --------
__global__ __launch_bounds__(256) void gemm2_kernel(
    const float* __restrict__ vq, const float* __restrict__ w2,
    float* __restrict__ out) {
  __shared__ float As[32 * PAD];  // vqT[ll][tt]
  __shared__ float Bs[32 * PAD];  // w2T[ll][ff]
  const int tid = threadIdx.x;
  const int blk = blockIdx.x;
  const int b = blk >> 6;
  const int rest = blk & 63;
  const int t0 = (rest >> 1) << 7;
  const int f0 = (rest & 1) << 7;
  const int tm = tid & 15;  // f-group
  const int tr = tid >> 4;  // t-group
  const float* vb = vq + (size_t)b * T_ * L_;
  float acc[8][8];
#pragma unroll
  for (int i = 0; i < 8; ++i)
#pragma unroll
    for (int j = 0; j < 8; ++j) acc[i][j] = 0.f;

  for (int l0 = 0; l0 < L_; l0 += 32) {
#pragma unroll
    for (int it = 0; it < 4; ++it) {
      int e = tid + it * 256;
      int t = e >> 3, q = e & 7;
      float4 v = *(const float4*)(vb + (size_t)(t0 + t) * L_ + l0 + q * 4);
      As[(q * 4 + 0) * PAD + t] = v.x;
      As[(q * 4 + 1) * PAD + t] = v.y;
      As[(q * 4 + 2) * PAD + t] = v.z;
      As[(q * 4 + 3) * PAD + t] = v.w;
    }
#pragma unroll
    for (int it = 0; it < 4; ++it) {
      int e = tid + it * 256;
      int f = e >> 3, q = e & 7;
      float4 v = *(const float4*)(w2 + (size_t)(f0 + f) * L_ + l0 + q * 4);
      Bs[(q * 4 + 0) * PAD + f] = v.x;
      Bs[(q * 4 + 1) * PAD + f] = v.y;
      Bs[(q * 4 + 2) * PAD + f] = v.z;
      Bs[(q * 4 + 3) * PAD + f] = v.w;
    }
    __syncthreads();
#pragma unroll
    for (int dd = 0; dd < 32; ++dd) {
      float a[8], w[8];
      *(float4*)&a[0] = *(const float4*)&As[dd * PAD + tr * 8];
      *(float4*)&a[4] = *(const float4*)&As[dd * PAD + tr * 8 + 4];
      *(float4*)&w[0] = *(const float4*)&Bs[dd * PAD + tm * 8];
      *(float4*)&w[4] = *(const float4*)&Bs[dd * PAD + tm * 8 + 4];
#pragma unroll
      for (int i = 0; i < 8; ++i)
#pragma unroll
        for (int j = 0; j < 8; ++j) acc[i][j] = fmaf(a[i], w[j], acc[i][j]);
    }
    __syncthreads();
  }
  // out[b][f0+tm*8+j][t0+tr*8+i]
  float* ob = out + ((size_t)b * F_ + f0) * T_ + t0;
#pragma unroll
  for (int j = 0; j < 8; ++j) {
    float* dst = ob + (size_t)(tm * 8 + j) * T_ + tr * 8;
    *(float4*)dst = make_float4(acc[0][j], acc[1][j], acc[2][j], acc[3][j]);
    *(float4*)(dst + 4) = make_float4(acc[4][j], acc[5][j], acc[6][j], acc[7][j]);
  }
}

extern "C" void kernel_launch(void* const* d_in, const int* in_sizes, int n_in,
                              void* d_out, int out_size, void* d_ws,
                              size_t ws_size, hipStream_t stream) {
  const float* in = (const float*)d_in[0];
  const float* w1 = (const float*)d_in[1];
  const float* w2 = (const float*)d_in[2];
  const float* cbs = (const float*)d_in[3];
  const float* gum = (const float*)d_in[4];
  float* out = (float*)d_out;
  float* vq_feat = out + 16777216;  // out1 region [B,T,L]
  float* qinds = out + 25165824;    // out2 region [B,TC,K]
  // scratch inside the out0 region: x (8,388,608 floats) + c2 (2048 floats).
  // gemm2 (last kernel) overwrites all of out0, so this is safe.
  float* x = out;
  float* c2 = out + 8388608;

  hipLaunchKernelGGL(gemm1_kernel, dim3(512), dim3(256), 0, stream, in, w1, x);
  hipLaunchKernelGGL(c2_kernel, dim3(8), dim3(256), 0, stream, cbs, c2);
  hipLaunchKernelGGL(vq_kernel, dim3(512), dim3(256), 0, stream, x, cbs, gum,
                     c2, vq_feat, qinds);
  hipLaunchKernelGGL(gemm2_kernel, dim3(1024), dim3(256), 0, stream, vq_feat,
                     w2, out);
}